// Round 1
// baseline (3876.125 us; speedup 1.0000x reference)
//
#include <hip/hip_runtime.h>
#include <cstdint>
#include <cstddef>

// ---------------- problem constants (fixed by setup_inputs) ----------------
static constexpr int D_IN = 784;
static constexpr int H1   = 2048;
static constexpr int H2   = 10;
static constexpr int KK   = 10;
static constexpr int UU   = 2832;   // D_IN + H1
static constexpr int LL   = 128;
static constexpr int BB   = 1024;
static constexpr int TT   = 20;     // time_window (setup_inputs fixes it)
static constexpr int NX   = BB * D_IN;   // 802816
static constexpr int HALF = NX / 2;      // 401408  (= 512*784, even split)

// ---------------- JAX threefry2x32 (20 rounds), bit-exact ----------------
__device__ __forceinline__ uint32_t rotl32(uint32_t x, int d) {
  return (x << d) | (x >> (32 - d));
}

__device__ __forceinline__ void threefry2x32(uint32_t k0, uint32_t k1,
                                             uint32_t& x0, uint32_t& x1) {
  uint32_t ks2 = k0 ^ k1 ^ 0x1BD11BDAu;
  x0 += k0; x1 += k1;
#define TF_R(r) { x0 += x1; x1 = rotl32(x1, (r)); x1 ^= x0; }
  TF_R(13) TF_R(15) TF_R(26) TF_R(6)
  x0 += k1;  x1 += ks2 + 1u;
  TF_R(17) TF_R(29) TF_R(16) TF_R(24)
  x0 += ks2; x1 += k0 + 2u;
  TF_R(13) TF_R(15) TF_R(26) TF_R(6)
  x0 += k0;  x1 += k1 + 3u;
  TF_R(17) TF_R(29) TF_R(16) TF_R(24)
  x0 += k1;  x1 += ks2 + 4u;
  TF_R(13) TF_R(15) TF_R(26) TF_R(6)
  x0 += ks2; x1 += k0 + 5u;
#undef TF_R
}

__device__ __forceinline__ float bits_to_unif(uint32_t b) {
  // (bits >> 9) | 0x3F800000, bitcast, -1.0f  ->  [0,1)
  uint32_t fb = (b >> 9) | 0x3F800000u;
  return __uint_as_float(fb) - 1.0f;
}

// ---------------- block-wide 3-way fp64 reduction + atomic ----------------
__device__ __forceinline__ double wave_red(double v) {
  #pragma unroll
  for (int off = 32; off > 0; off >>= 1) v += __shfl_down(v, off, 64);
  return v;
}

__device__ __forceinline__ void block_reduce3(double s0, double s1, double s2,
                                              double* acc) {
  __shared__ double lds[3][4];
  int lane = threadIdx.x & 63, w = threadIdx.x >> 6;
  s0 = wave_red(s0); s1 = wave_red(s1); s2 = wave_red(s2);
  if (lane == 0) { lds[0][w] = s0; lds[1][w] = s1; lds[2][w] = s2; }
  __syncthreads();
  if (threadIdx.x == 0) {
    double t0 = 0, t1 = 0, t2 = 0;
    #pragma unroll
    for (int i = 0; i < 4; i++) { t0 += lds[0][i]; t1 += lds[1][i]; t2 += lds[2][i]; }
    atomicAdd(&acc[0], t0); atomicAdd(&acc[1], t1); atomicAdd(&acc[2], t2);
  }
}

// ---------------- precompute val1/val2 (v1[u], v2[u]) ----------------
__global__ void precompute_vals(const float* __restrict__ vec,
                                const int* __restrict__ cnt,
                                float* __restrict__ v1, float* __restrict__ v2) {
  int id = blockIdx.x * 256 + threadIdx.x;
  if (id >= KK * UU) return;
  int k = id / UU, u = id - k * UU;
  int c = cnt[(size_t)k * UU + u];
  const float* p = vec + ((size_t)k * UU + u) * LL;
  int last = -1;
  for (int l = LL - 1; l >= 0; l--) {
    if (p[l] != 0.0f) { last = l; break; }
  }
  if (c > 0) {
    if (last >= 0) atomicAdd(&v1[u], (float)(last - 1));  // last_idx - 1 (can be -1)
    atomicAdd(&v2[u], (float)c);
  }
}

// ---------------- per-step spike generation (exact threefry) ----------------
__global__ __launch_bounds__(256)
void gen_x(const float* __restrict__ input, float* __restrict__ x,
           const float* __restrict__ v1, const float* __restrict__ v2,
           double* __restrict__ acc, int t) {
  int j = blockIdx.x * 256 + threadIdx.x;   // [0, HALF), grid exact
  // fold_in(key(42), t) == threefry((0,42),(0,t))
  uint32_t f0 = 0u, f1 = (uint32_t)t;
  threefry2x32(0u, 42u, f0, f1);
  // uniform bits: pair (j, j+HALF)
  uint32_t c0 = (uint32_t)j, c1 = (uint32_t)(j + HALF);
  threefry2x32(f0, f1, c0, c1);
  float u0 = bits_to_unif(c0);
  float u1 = bits_to_unif(c1);
  float x0 = (input[j]        > u0) ? 1.0f : 0.0f;
  float x1v = (input[j + HALF] > u1) ? 1.0f : 0.0f;
  x[j]        = x0;
  x[j + HALF] = x1v;
  int d = j % D_IN;           // j+HALF has the same d (HALF = 512*784)
  float xsum = x0 + x1v;
  double s0 = (double)xsum * (double)v1[d];
  double s1 = (double)xsum * (double)v2[d];
  double s2 = (double)xsum;
  block_reduce3(s0, s1, s2, acc);
}

// ---------------- h1 membrane update: fp64 GEMM 1024x2048x784 ----------------
// C[m,n] = sum_k x[m,k] * W1[n,k]; then decay+spike epilogue.
__global__ __launch_bounds__(256)
void step_h1(const float* __restrict__ x, const float* __restrict__ W1,
             const float* __restrict__ b1, double* __restrict__ h1m,
             float* __restrict__ h1s, const float* __restrict__ v1,
             const float* __restrict__ v2, double* __restrict__ acc) {
  __shared__ double As[16][66];   // x tile, [k][m], padded
  __shared__ double Bs[16][66];   // W1 tile, [k][n], padded
  int tid = threadIdx.x;
  int tx = tid & 15, ty = tid >> 4;
  int m0 = blockIdx.y * 64, n0 = blockIdx.x * 64;
  int r = tid >> 2, c4 = (tid & 3) << 2;   // staging: row r, 4 cols at c4

  double accd[4][4] = {{0.0}};

  for (int k0 = 0; k0 < D_IN; k0 += 16) {
    float4 xv = *(const float4*)(x  + (size_t)(m0 + r) * D_IN + k0 + c4);
    float4 wv = *(const float4*)(W1 + (size_t)(n0 + r) * D_IN + k0 + c4);
    As[c4 + 0][r] = (double)xv.x; As[c4 + 1][r] = (double)xv.y;
    As[c4 + 2][r] = (double)xv.z; As[c4 + 3][r] = (double)xv.w;
    Bs[c4 + 0][r] = (double)wv.x; Bs[c4 + 1][r] = (double)wv.y;
    Bs[c4 + 2][r] = (double)wv.z; Bs[c4 + 3][r] = (double)wv.w;
    __syncthreads();
    #pragma unroll
    for (int k = 0; k < 16; k++) {
      double av[4], bv[4];
      #pragma unroll
      for (int i = 0; i < 4; i++) av[i] = As[k][ty * 4 + i];
      #pragma unroll
      for (int j = 0; j < 4; j++) bv[j] = Bs[k][tx * 4 + j];
      #pragma unroll
      for (int i = 0; i < 4; i++)
        #pragma unroll
        for (int j = 0; j < 4; j++)
          accd[i][j] += av[i] * bv[j];
    }
    __syncthreads();
  }

  double s0 = 0, s1 = 0, s2 = 0;
  #pragma unroll
  for (int i = 0; i < 4; i++) {
    int gm = m0 + ty * 4 + i;
    #pragma unroll
    for (int j = 0; j < 4; j++) {
      int gn = n0 + tx * 4 + j;
      size_t idx = (size_t)gm * H1 + gn;
      double mprev = h1m[idx];
      float  sprev = h1s[idx];
      double m = mprev * 0.2 * (1.0 - (double)sprev) + accd[i][j] + (double)b1[gn];
      float  s = (m > 0.5) ? 1.0f : 0.0f;
      h1m[idx] = m;
      h1s[idx] = s;
      if (s != 0.0f) {
        s0 += (double)v1[D_IN + gn];
        s1 += (double)v2[D_IN + gn];
        s2 += 1.0;
      }
    }
  }
  block_reduce3(s0, s1, s2, acc);
}

// ---------------- h2 update: 1024 blocks, dot over 2048 ----------------
__global__ __launch_bounds__(256)
void step_h2(const float* __restrict__ h1s, const float* __restrict__ W2,
             const float* __restrict__ b2, double* __restrict__ h2m,
             float* __restrict__ h2s, float* __restrict__ h2sum) {
  __shared__ double red[H2][256];
  int b = blockIdx.x, tid = threadIdx.x;
  double p[H2];
  #pragma unroll
  for (int j = 0; j < H2; j++) p[j] = 0.0;
  for (int i = tid; i < H1; i += 256) {
    float hv = h1s[(size_t)b * H1 + i];
    if (hv != 0.0f) {
      #pragma unroll
      for (int j = 0; j < H2; j++) p[j] += (double)W2[(size_t)j * H1 + i];
    }
  }
  #pragma unroll
  for (int j = 0; j < H2; j++) red[j][tid] = p[j];
  __syncthreads();
  for (int off = 128; off > 0; off >>= 1) {
    if (tid < off) {
      #pragma unroll
      for (int j = 0; j < H2; j++) red[j][tid] += red[j][tid + off];
    }
    __syncthreads();
  }
  if (tid < H2) {
    int j = tid;
    size_t idx = (size_t)b * H2 + j;
    double m = h2m[idx] * 0.2 * (1.0 - (double)h2s[idx]) + red[j][0] + (double)b2[j];
    float  s = (m > 0.5) ? 1.0f : 0.0f;
    h2m[idx] = m;
    h2s[idx] = s;
    h2sum[idx] += s;
  }
}

// ---------------- finalize: outputs = h2sum/T, then a1,a2,cs ----------------
__global__ void finalize(const float* __restrict__ h2sum,
                         const double* __restrict__ acc, float* __restrict__ out) {
  int i = blockIdx.x * 256 + threadIdx.x;
  if (i < BB * H2) out[i] = h2sum[i] / (float)TT;
  if (i == 0) {
    out[BB * H2 + 0] = (float)acc[0];
    out[BB * H2 + 1] = (float)acc[1];
    out[BB * H2 + 2] = (float)acc[2];
  }
}

// ---------------- launch ----------------
extern "C" void kernel_launch(void* const* d_in, const int* in_sizes, int n_in,
                              void* d_out, int out_size, void* d_ws, size_t ws_size,
                              hipStream_t stream) {
  const float* input = (const float*)d_in[0];
  const float* W1    = (const float*)d_in[1];
  const float* b1    = (const float*)d_in[2];
  const float* W2    = (const float*)d_in[3];
  const float* b2    = (const float*)d_in[4];
  const float* cmv   = (const float*)d_in[5];
  const int*   cmc   = (const int*)d_in[6];
  // d_in[7] = time_window (always 20 per setup_inputs)

  // workspace layout (doubles first for alignment)
  double* h1m  = (double*)d_ws;                       // 1024*2048
  double* h2m  = h1m + (size_t)BB * H1;               // 1024*10
  double* acc  = h2m + (size_t)BB * H2;               // 3 (+pad to 8)
  float*  h1s  = (float*)(acc + 8);                   // 1024*2048
  float*  h2s  = h1s + (size_t)BB * H1;               // 1024*10
  float*  h2sm = h2s + (size_t)BB * H2;               // 1024*10
  float*  v1   = h2sm + (size_t)BB * H2;              // 2832
  float*  v2   = v1 + UU;                             // 2832
  float*  xbuf = v2 + UU;                             // 1024*784

  size_t zero_bytes = ((size_t)BB * H1 + (size_t)BB * H2 + 8) * sizeof(double)
                    + ((size_t)BB * H1 + 2 * (size_t)BB * H2 + 2 * (size_t)UU) * sizeof(float);
  hipMemsetAsync(d_ws, 0, zero_bytes, stream);

  precompute_vals<<<(KK * UU + 255) / 256, 256, 0, stream>>>(cmv, cmc, v1, v2);

  for (int t = 0; t < TT; t++) {
    gen_x<<<HALF / 256, 256, 0, stream>>>(input, xbuf, v1, v2, acc, t);
    step_h1<<<dim3(H1 / 64, BB / 64), 256, 0, stream>>>(xbuf, W1, b1, h1m, h1s, v1, v2, acc);
    step_h2<<<BB, 256, 0, stream>>>(h1s, W2, b2, h2m, h2s, h2sm);
  }

  finalize<<<(BB * H2 + 255) / 256, 256, 0, stream>>>(h2sm, acc, (float*)d_out);
}

// Round 2
// 2517.240 us; speedup vs baseline: 1.5398x; 1.5398x over previous
//
#include <hip/hip_runtime.h>
#include <cstdint>
#include <cstddef>

// ---------------- problem constants (fixed by setup_inputs) ----------------
static constexpr int D_IN = 784;
static constexpr int H1   = 2048;
static constexpr int H2   = 10;
static constexpr int KK   = 10;
static constexpr int UU   = 2832;   // D_IN + H1
static constexpr int LL   = 128;
static constexpr int BB   = 1024;
static constexpr int TT   = 20;     // time_window (setup_inputs fixes it)
static constexpr int NX   = BB * D_IN;   // 802816
static constexpr int HALF = NX / 2;      // 401408  (= 512*784)

typedef double v4d __attribute__((ext_vector_type(4)));

// ---------------- JAX threefry2x32 (20 rounds), bit-exact ----------------
__device__ __forceinline__ uint32_t rotl32(uint32_t x, int d) {
  return (x << d) | (x >> (32 - d));
}

__device__ __forceinline__ void threefry2x32(uint32_t k0, uint32_t k1,
                                             uint32_t& x0, uint32_t& x1) {
  uint32_t ks2 = k0 ^ k1 ^ 0x1BD11BDAu;
  x0 += k0; x1 += k1;
#define TF_R(r) { x0 += x1; x1 = rotl32(x1, (r)); x1 ^= x0; }
  TF_R(13) TF_R(15) TF_R(26) TF_R(6)
  x0 += k1;  x1 += ks2 + 1u;
  TF_R(17) TF_R(29) TF_R(16) TF_R(24)
  x0 += ks2; x1 += k0 + 2u;
  TF_R(13) TF_R(15) TF_R(26) TF_R(6)
  x0 += k0;  x1 += k1 + 3u;
  TF_R(17) TF_R(29) TF_R(16) TF_R(24)
  x0 += k1;  x1 += ks2 + 4u;
  TF_R(13) TF_R(15) TF_R(26) TF_R(6)
  x0 += ks2; x1 += k0 + 5u;
#undef TF_R
}

__device__ __forceinline__ float bits_to_unif(uint32_t b) {
  uint32_t fb = (b >> 9) | 0x3F800000u;
  return __uint_as_float(fb) - 1.0f;
}

// ---------------- block-wide 3-way fp64 reduction + atomic ----------------
__device__ __forceinline__ double wave_red(double v) {
  #pragma unroll
  for (int off = 32; off > 0; off >>= 1) v += __shfl_down(v, off, 64);
  return v;
}

__device__ __forceinline__ void block_reduce3(double s0, double s1, double s2,
                                              double* gacc) {
  __shared__ double lds[3][4];
  int lane = threadIdx.x & 63, w = threadIdx.x >> 6;
  s0 = wave_red(s0); s1 = wave_red(s1); s2 = wave_red(s2);
  if (lane == 0) { lds[0][w] = s0; lds[1][w] = s1; lds[2][w] = s2; }
  __syncthreads();
  if (threadIdx.x == 0) {
    double t0 = 0, t1 = 0, t2 = 0;
    #pragma unroll
    for (int i = 0; i < 4; i++) { t0 += lds[0][i]; t1 += lds[1][i]; t2 += lds[2][i]; }
    atomicAdd(&gacc[0], t0); atomicAdd(&gacc[1], t1); atomicAdd(&gacc[2], t2);
  }
}

// ---------------- precompute val1/val2 (one wave per (k,u), ballot) ----------------
__global__ __launch_bounds__(256)
void precompute_vals(const float* __restrict__ vec, const int* __restrict__ cnt,
                     float* __restrict__ v1, float* __restrict__ v2) {
  int gw = (blockIdx.x * 256 + threadIdx.x) >> 6;   // global wave id = k*UU+u
  int lane = threadIdx.x & 63;
  if (gw >= KK * UU) return;
  const float* p = vec + (size_t)gw * LL;
  float a = p[lane];
  float b = p[lane + 64];
  unsigned long long mlo = __ballot(a != 0.0f);
  unsigned long long mhi = __ballot(b != 0.0f);
  if (lane == 0) {
    int u = gw % UU;
    int c = cnt[gw];
    int last = mhi ? (127 - __builtin_clzll(mhi))
                   : (mlo ? (63 - __builtin_clzll(mlo)) : -1);
    if (c > 0) {
      if (last >= 0) atomicAdd(&v1[u], (float)(last - 1));
      atomicAdd(&v2[u], (float)c);
    }
  }
}

// ---------------- per-step spike generation (exact threefry, x4 vec) ----------------
__global__ __launch_bounds__(256)
void gen_x(const float* __restrict__ input, float* __restrict__ x,
           const float* __restrict__ v1, const float* __restrict__ v2,
           double* __restrict__ gacc, int t) {
  int j0 = (blockIdx.x * 256 + threadIdx.x) * 4;   // [0, HALF) step 4
  uint32_t f0 = 0u, f1 = (uint32_t)t;
  threefry2x32(0u, 42u, f0, f1);
  float4 in0 = *(const float4*)(input + j0);
  float4 in1 = *(const float4*)(input + j0 + HALF);
  float xs[8];
  #pragma unroll
  for (int q = 0; q < 4; q++) {
    uint32_t c0 = (uint32_t)(j0 + q), c1 = (uint32_t)(j0 + q + HALF);
    threefry2x32(f0, f1, c0, c1);
    float u0 = bits_to_unif(c0);
    float u1 = bits_to_unif(c1);
    float i0 = (&in0.x)[q], i1 = (&in1.x)[q];
    xs[q]     = (i0 > u0) ? 1.0f : 0.0f;
    xs[4 + q] = (i1 > u1) ? 1.0f : 0.0f;
  }
  *(float4*)(x + j0)        = make_float4(xs[0], xs[1], xs[2], xs[3]);
  *(float4*)(x + j0 + HALF) = make_float4(xs[4], xs[5], xs[6], xs[7]);
  int d0 = j0 % D_IN;    // 784 % 4 == 0 so d0+3 <= 783, no wrap; same d for j+HALF
  double s0 = 0, s1 = 0, s2 = 0;
  #pragma unroll
  for (int q = 0; q < 4; q++) {
    double xsum = (double)(xs[q] + xs[4 + q]);
    s0 += xsum * (double)v1[d0 + q];
    s1 += xsum * (double)v2[d0 + q];
    s2 += xsum;
  }
  block_reduce3(s0, s1, s2, gacc);
}

// ---------------- h1 update: fp64 MFMA GEMM 1024x2048x784 ----------------
// C[m,n] = sum_k x[m,k]*W1[n,k]; decay+spike epilogue; v1/v2 spike reduction.
// Block: 256 thr = 4 waves; tile 64m x 64n; wave -> 32x32 quadrant (4 MFMA tiles).
__global__ __launch_bounds__(256)
void step_h1(const float* __restrict__ x, const float* __restrict__ W1,
             const float* __restrict__ b1, double* __restrict__ h1m,
             float* __restrict__ h1s, const float* __restrict__ v1,
             const float* __restrict__ v2, double* __restrict__ gacc) {
  constexpr int SP = 66;                 // row stride in doubles (64 + 2 pad)
  __shared__ double As[16 * SP];         // [k][m], m-tile of x
  __shared__ double Bs[16 * SP];         // [k][n], n-tile of W1
  int tid = threadIdx.x;
  int lane = tid & 63, wv = tid >> 6;
  int mw = wv >> 1, nw = wv & 1;         // wave quadrant
  int la = lane & 15;                    // row/col within 16
  int kq = lane >> 4;                    // k within quad (0..3)
  int m0 = blockIdx.y * 64, n0 = blockIdx.x * 64;

  int r = tid >> 2, c4 = (tid & 3) << 2; // staging: row r, k-cols c4..c4+3
  const float* xp = x  + (size_t)(m0 + r) * D_IN + c4;
  const float* wp = W1 + (size_t)(n0 + r) * D_IN + c4;

  v4d a00 = {0,0,0,0}, a01 = {0,0,0,0}, a10 = {0,0,0,0}, a11 = {0,0,0,0};

  float4 xv = *(const float4*)(xp);
  float4 wv4 = *(const float4*)(wp);

  for (int k0 = 0; k0 < D_IN; k0 += 16) {
    As[(c4 + 0) * SP + r] = (double)xv.x;
    As[(c4 + 1) * SP + r] = (double)xv.y;
    As[(c4 + 2) * SP + r] = (double)xv.z;
    As[(c4 + 3) * SP + r] = (double)xv.w;
    Bs[(c4 + 0) * SP + r] = (double)wv4.x;
    Bs[(c4 + 1) * SP + r] = (double)wv4.y;
    Bs[(c4 + 2) * SP + r] = (double)wv4.z;
    Bs[(c4 + 3) * SP + r] = (double)wv4.w;
    __syncthreads();
    if (k0 + 16 < D_IN) {               // register prefetch of next tile
      xv  = *(const float4*)(xp + k0 + 16);
      wv4 = *(const float4*)(wp + k0 + 16);
    }
    #pragma unroll
    for (int q = 0; q < 4; q++) {
      int krow = q * 4 + kq;
      double av0 = As[krow * SP + mw * 32 + la];
      double av1 = As[krow * SP + mw * 32 + 16 + la];
      double bv0 = Bs[krow * SP + nw * 32 + la];
      double bv1 = Bs[krow * SP + nw * 32 + 16 + la];
      a00 = __builtin_amdgcn_mfma_f64_16x16x4f64(av0, bv0, a00, 0, 0, 0);
      a01 = __builtin_amdgcn_mfma_f64_16x16x4f64(av0, bv1, a01, 0, 0, 0);
      a10 = __builtin_amdgcn_mfma_f64_16x16x4f64(av1, bv0, a10, 0, 0, 0);
      a11 = __builtin_amdgcn_mfma_f64_16x16x4f64(av1, bv1, a11, 0, 0, 0);
    }
    __syncthreads();
  }

  // epilogue: D layout col=lane&15, row=(lane>>4)*4+reg per 16x16 tile
  double s0 = 0, s1 = 0, s2 = 0;
  #pragma unroll
  for (int mt = 0; mt < 2; mt++) {
    #pragma unroll
    for (int nt = 0; nt < 2; nt++) {
      const v4d& av = (mt == 0) ? (nt == 0 ? a00 : a01) : (nt == 0 ? a10 : a11);
      int gn = n0 + nw * 32 + nt * 16 + la;
      double bias = (double)b1[gn];
      double v1n = v1[D_IN + gn], v2n = v2[D_IN + gn];
      #pragma unroll
      for (int v = 0; v < 4; v++) {
        int gm = m0 + mw * 32 + mt * 16 + kq * 4 + v;
        size_t idx = (size_t)gm * H1 + gn;
        double mprev = h1m[idx];
        float  sprev = h1s[idx];
        double mnew = mprev * 0.2 * (1.0 - (double)sprev) + av[v] + bias;
        float  s = (mnew > 0.5) ? 1.0f : 0.0f;
        h1m[idx] = mnew;
        h1s[idx] = s;
        if (s != 0.0f) { s0 += v1n; s1 += v2n; s2 += 1.0; }
      }
    }
  }
  block_reduce3(s0, s1, s2, gacc);
}

// ---------------- h2 update: one wave per batch row, shuffle reduce ----------------
__global__ __launch_bounds__(256)
void step_h2(const float* __restrict__ h1s, const float* __restrict__ W2,
             const float* __restrict__ b2, double* __restrict__ h2m,
             float* __restrict__ h2s, float* __restrict__ h2sum,
             const double* __restrict__ gacc, float* __restrict__ out, int last) {
  int lane = threadIdx.x & 63, wvid = threadIdx.x >> 6;
  int b = blockIdx.x * 4 + wvid;
  double p[H2] = {};
  const float* hrow = h1s + (size_t)b * H1;
  for (int i = lane; i < H1; i += 64) {
    double hv = (double)hrow[i];
    #pragma unroll
    for (int j = 0; j < H2; j++) p[j] += hv * (double)W2[j * H1 + i];
  }
  #pragma unroll
  for (int j = 0; j < H2; j++) {
    double v = p[j];
    #pragma unroll
    for (int off = 32; off > 0; off >>= 1) v += __shfl_xor(v, off, 64);
    p[j] = v;
  }
  if (lane < H2) {
    double red = 0;
    #pragma unroll
    for (int j = 0; j < H2; j++) red = (lane == j) ? p[j] : red;
    size_t idx = (size_t)b * H2 + lane;
    double m = h2m[idx] * 0.2 * (1.0 - (double)h2s[idx]) + red + (double)b2[lane];
    float s = (m > 0.5) ? 1.0f : 0.0f;
    float ns = h2sum[idx] + s;
    h2m[idx] = m; h2s[idx] = s; h2sum[idx] = ns;
    if (last) out[idx] = (float)((double)ns / (double)TT);
  }
  if (last && blockIdx.x == 0 && threadIdx.x < 3)
    out[(size_t)BB * H2 + threadIdx.x] = (float)gacc[threadIdx.x];
}

// ---------------- launch ----------------
extern "C" void kernel_launch(void* const* d_in, const int* in_sizes, int n_in,
                              void* d_out, int out_size, void* d_ws, size_t ws_size,
                              hipStream_t stream) {
  const float* input = (const float*)d_in[0];
  const float* W1    = (const float*)d_in[1];
  const float* b1    = (const float*)d_in[2];
  const float* W2    = (const float*)d_in[3];
  const float* b2    = (const float*)d_in[4];
  const float* cmv   = (const float*)d_in[5];
  const int*   cmc   = (const int*)d_in[6];

  double* h1m  = (double*)d_ws;                       // 1024*2048
  double* h2m  = h1m + (size_t)BB * H1;               // 1024*10
  double* gacc = h2m + (size_t)BB * H2;               // 3 (+pad to 8)
  float*  h1s  = (float*)(gacc + 8);                  // 1024*2048
  float*  h2s  = h1s + (size_t)BB * H1;               // 1024*10
  float*  h2sm = h2s + (size_t)BB * H2;               // 1024*10
  float*  v1   = h2sm + (size_t)BB * H2;              // 2832
  float*  v2   = v1 + UU;                             // 2832
  float*  xbuf = v2 + UU;                             // 1024*784

  size_t zero_bytes = ((size_t)BB * H1 + (size_t)BB * H2 + 8) * sizeof(double)
                    + ((size_t)BB * H1 + 2 * (size_t)BB * H2 + 2 * (size_t)UU) * sizeof(float);
  hipMemsetAsync(d_ws, 0, zero_bytes, stream);

  precompute_vals<<<(KK * UU) / 4, 256, 0, stream>>>(cmv, cmc, v1, v2);

  for (int t = 0; t < TT; t++) {
    gen_x<<<HALF / 1024, 256, 0, stream>>>(input, xbuf, v1, v2, gacc, t);
    step_h1<<<dim3(H1 / 64, BB / 64), 256, 0, stream>>>(xbuf, W1, b1, h1m, h1s, v1, v2, gacc);
    step_h2<<<BB / 4, 256, 0, stream>>>(h1s, W2, b2, h2m, h2s, h2sm, gacc,
                                        (float*)d_out, (t == TT - 1) ? 1 : 0);
  }
}

// Round 3
// 1173.939 us; speedup vs baseline: 3.3018x; 2.1443x over previous
//
#include <hip/hip_runtime.h>
#include <cstdint>
#include <cstddef>

// ---------------- problem constants (fixed by setup_inputs) ----------------
static constexpr int D_IN = 784;
static constexpr int H1   = 2048;
static constexpr int H2   = 10;
static constexpr int KK   = 10;
static constexpr int UU   = 2832;   // D_IN + H1
static constexpr int LL   = 128;
static constexpr int BB   = 1024;
static constexpr int TT   = 20;
static constexpr int HALF = BB * D_IN / 2;   // 401408 = 512*784
static constexpr int NCH  = 25;              // K chunks of 32 (784 -> 800 padded)

typedef int v4i  __attribute__((ext_vector_type(4)));
typedef int v16i __attribute__((ext_vector_type(16)));

// ---------------- JAX threefry2x32 (20 rounds), bit-exact ----------------
__device__ __forceinline__ uint32_t rotl32(uint32_t x, int d) {
  return (x << d) | (x >> (32 - d));
}
__device__ __forceinline__ void threefry2x32(uint32_t k0, uint32_t k1,
                                             uint32_t& x0, uint32_t& x1) {
  uint32_t ks2 = k0 ^ k1 ^ 0x1BD11BDAu;
  x0 += k0; x1 += k1;
#define TF_R(r) { x0 += x1; x1 = rotl32(x1, (r)); x1 ^= x0; }
  TF_R(13) TF_R(15) TF_R(26) TF_R(6)
  x0 += k1;  x1 += ks2 + 1u;
  TF_R(17) TF_R(29) TF_R(16) TF_R(24)
  x0 += ks2; x1 += k0 + 2u;
  TF_R(13) TF_R(15) TF_R(26) TF_R(6)
  x0 += k0;  x1 += k1 + 3u;
  TF_R(17) TF_R(29) TF_R(16) TF_R(24)
  x0 += k1;  x1 += ks2 + 4u;
  TF_R(13) TF_R(15) TF_R(26) TF_R(6)
  x0 += ks2; x1 += k0 + 5u;
#undef TF_R
}
__device__ __forceinline__ float bits_to_unif(uint32_t b) {
  uint32_t fb = (b >> 9) | 0x3F800000u;
  return __uint_as_float(fb) - 1.0f;
}

// ---------------- block-wide 3-way fp64 reduction + atomic ----------------
__device__ __forceinline__ double wave_red(double v) {
  #pragma unroll
  for (int off = 32; off > 0; off >>= 1) v += __shfl_down(v, off, 64);
  return v;
}
__device__ __forceinline__ void block_reduce3(double s0, double s1, double s2,
                                              double* gacc) {
  __shared__ double lds[3][4];
  int lane = threadIdx.x & 63, w = threadIdx.x >> 6;
  s0 = wave_red(s0); s1 = wave_red(s1); s2 = wave_red(s2);
  if (lane == 0) { lds[0][w] = s0; lds[1][w] = s1; lds[2][w] = s2; }
  __syncthreads();
  if (threadIdx.x == 0) {
    double t0 = 0, t1 = 0, t2 = 0;
    #pragma unroll
    for (int i = 0; i < 4; i++) { t0 += lds[0][i]; t1 += lds[1][i]; t2 += lds[2][i]; }
    atomicAdd(&gacc[0], t0); atomicAdd(&gacc[1], t1); atomicAdd(&gacc[2], t2);
  }
}

// ---------------- precompute val1/val2 (one wave per (k,u), ballot) ----------------
__global__ __launch_bounds__(256)
void precompute_vals(const float* __restrict__ vec, const int* __restrict__ cnt,
                     float* __restrict__ v1, float* __restrict__ v2) {
  int gw = (blockIdx.x * 256 + threadIdx.x) >> 6;
  int lane = threadIdx.x & 63;
  if (gw >= KK * UU) return;
  const float* p = vec + (size_t)gw * LL;
  float a = p[lane];
  float b = p[lane + 64];
  unsigned long long mlo = __ballot(a != 0.0f);
  unsigned long long mhi = __ballot(b != 0.0f);
  if (lane == 0) {
    int u = gw % UU;
    int c = cnt[gw];
    int last = mhi ? (127 - __builtin_clzll(mhi))
                   : (mlo ? (63 - __builtin_clzll(mlo)) : -1);
    if (c > 0) {
      if (last >= 0) atomicAdd(&v1[u], (float)(last - 1));
      atomicAdd(&v2[u], (float)c);
    }
  }
}

// ---------------- W2 transpose: W2T[i][j] = W2[j][i] ----------------
__global__ void make_w2t(const float* __restrict__ W2, float* __restrict__ W2T) {
  int i = blockIdx.x * 256 + threadIdx.x;
  if (i >= H1) return;
  #pragma unroll
  for (int j = 0; j < H2; j++) W2T[i * H2 + j] = W2[j * H1 + i];
}

// ---------------- W1 -> 5 signed base-256 int8 limbs, B-fragment order ----------
// W1L entry index: ((ntile*NCH + chunk)*5 + limb)*64 + lane  (16 B each)
// lane mapping: n = ntile*32 + (lane&31), k = chunk*32 + (lane>>5)*16 + j
__global__ __launch_bounds__(256)
void make_limbs(const float* __restrict__ W1, v4i* __restrict__ W1L) {
  int tid = blockIdx.x * 256 + threadIdx.x;   // 64*NCH*64 = 102400
  int lane = tid & 63;
  int tc = tid >> 6;                           // ntile*NCH + chunk
  int n = ((tc / NCH) << 5) + (lane & 31);
  int chunk = tc % NCH;
  int k0 = chunk * 32 + (lane >> 5) * 16;
  union { v4i v; signed char b[16]; } d[5];
  #pragma unroll
  for (int j = 0; j < 16; j++) {
    long long F = 0;
    int k = k0 + j;
    if (k < D_IN) {
      double w = (double)W1[(size_t)n * D_IN + k];
      F = llround(w * 0x1p40);
    }
    #pragma unroll
    for (int l = 0; l < 5; l++) {
      int dig = (int)((F + 128) & 255) - 128;
      d[l].b[j] = (signed char)dig;
      F = (F - dig) >> 8;
    }
  }
  #pragma unroll
  for (int l = 0; l < 5; l++) W1L[(size_t)(tc * 5 + l) * 64 + lane] = d[l].v;
}

// ---------------- spike generation, A-fragment order, + a1/a2/cs terms ----------
// XA entry index: (mtile*NCH + chunk)*64 + lane
// lane mapping: m = mtile*32 + (lane&31), k = chunk*32 + (lane>>5)*16 + j
__device__ __forceinline__ void gen_wave(int gw, int t,
    const float* __restrict__ input, v4i* __restrict__ XA,
    const float* __restrict__ v1, const float* __restrict__ v2,
    double& s0, double& s1, double& s2) {
  int lane = threadIdx.x & 63;
  int mtile = gw / NCH, chunk = gw - mtile * NCH;   // mtile in [0,16): m < 512
  int m = (mtile << 5) + (lane & 31);
  int k0 = chunk * 32 + (lane >> 5) * 16;
  uint32_t f0 = 0u, f1 = (uint32_t)t;
  threefry2x32(0u, 42u, f0, f1);
  union { v4i v; unsigned char b[16]; } r0, r1;
  s0 = 0; s1 = 0; s2 = 0;
  if (k0 < D_IN) {   // whole 16-group valid (784 = 24*32+16: only chunk24/half1 invalid)
    #pragma unroll
    for (int j = 0; j < 16; j++) {
      int k = k0 + j;
      uint32_t c0 = (uint32_t)(m * D_IN + k), c1 = c0 + (uint32_t)HALF;
      threefry2x32(f0, f1, c0, c1);
      float u0 = bits_to_unif(c0), u1 = bits_to_unif(c1);
      float i0 = input[(size_t)m * D_IN + k];
      float i1 = input[(size_t)(m + 512) * D_IN + k];
      unsigned char x0 = (i0 > u0) ? 1 : 0;
      unsigned char x1 = (i1 > u1) ? 1 : 0;
      r0.b[j] = x0; r1.b[j] = x1;
      double xsum = (double)(x0 + x1);
      s0 += xsum * (double)v1[k];
      s1 += xsum * (double)v2[k];
      s2 += xsum;
    }
  } else {
    r0.v = (v4i){0, 0, 0, 0};
    r1.v = (v4i){0, 0, 0, 0};
  }
  XA[(size_t)(mtile * NCH + chunk) * 64 + lane] = r0.v;
  XA[(size_t)((mtile + 16) * NCH + chunk) * 64 + lane] = r1.v;   // partner m+512
}

__global__ __launch_bounds__(256)
void gen0(const float* __restrict__ input, v4i* __restrict__ XA,
          const float* __restrict__ v1, const float* __restrict__ v2,
          double* __restrict__ gacc) {
  int gw = blockIdx.x * 4 + (threadIdx.x >> 6);    // 400 waves
  double s0, s1, s2;
  gen_wave(gw, 0, input, XA, v1, v2, s0, s1, s2);
  block_reduce3(s0, s1, s2, gacc);
}

// ---------------- h1 update: 5-limb i8 MFMA GEMM, no LDS, no barriers ----------
// Wave tile 32m x 32n; block = 4 waves = 64x64; grid (32 n-blocks, 16 m-blocks).
__global__ __launch_bounds__(256)
void step_h1(const v4i* __restrict__ XA, const v4i* __restrict__ W1L,
             const float* __restrict__ b1, double* __restrict__ h1m,
             unsigned char* __restrict__ h1s, const float* __restrict__ v1,
             const float* __restrict__ v2, double* __restrict__ gacc) {
  int lane = threadIdx.x & 63, wv = threadIdx.x >> 6;
  int mtile = blockIdx.y * 2 + (wv >> 1);
  int ntile = blockIdx.x * 2 + (wv & 1);
  const v4i* ap = XA  + (size_t)(mtile * NCH) * 64 + lane;
  const v4i* bp = W1L + (size_t)(ntile * NCH) * 5 * 64 + lane;

  v16i a0 = {}, a1 = {}, a2 = {}, a3 = {}, a4 = {};
  v4i A  = ap[0];
  v4i B0 = bp[0], B1 = bp[64], B2 = bp[128], B3 = bp[192], B4 = bp[256];

  #pragma unroll 1
  for (int c = 0; c < NCH; c++) {
    v4i An, C0, C1, C2, C3, C4;
    if (c < NCH - 1) {
      An = ap[(c + 1) * 64];
      const v4i* bq = bp + (size_t)(c + 1) * 5 * 64;
      C0 = bq[0]; C1 = bq[64]; C2 = bq[128]; C3 = bq[192]; C4 = bq[256];
    }
    a0 = __builtin_amdgcn_mfma_i32_32x32x32_i8(A, B0, a0, 0, 0, 0);
    a1 = __builtin_amdgcn_mfma_i32_32x32x32_i8(A, B1, a1, 0, 0, 0);
    a2 = __builtin_amdgcn_mfma_i32_32x32x32_i8(A, B2, a2, 0, 0, 0);
    a3 = __builtin_amdgcn_mfma_i32_32x32x32_i8(A, B3, a3, 0, 0, 0);
    a4 = __builtin_amdgcn_mfma_i32_32x32x32_i8(A, B4, a4, 0, 0, 0);
    A = An; B0 = C0; B1 = C1; B2 = C2; B3 = C3; B4 = C4;
  }

  // C/D layout (32x32, dtype-independent): col=lane&31, row=(r&3)+8*(r>>2)+4*(lane>>5)
  int col = lane & 31;
  int rbase = (lane >> 5) * 4;
  int gn = (ntile << 5) + col;
  double bias = (double)b1[gn];
  double v1n = (double)v1[D_IN + gn], v2n = (double)v2[D_IN + gn];
  double s0 = 0, s1 = 0, s2 = 0;
  #pragma unroll
  for (int r = 0; r < 16; r++) {
    int row = (r & 3) + 8 * (r >> 2) + rbase;
    int gm = (mtile << 5) + row;
    double dot = ((((double)a4[r] * 256.0 + (double)a3[r]) * 256.0
                   + (double)a2[r]) * 256.0 + (double)a1[r]) * 256.0 + (double)a0[r];
    dot *= 0x1p-40;
    size_t idx = (size_t)gm * H1 + gn;
    double mprev = h1m[idx];
    double sprev = (mprev > 0.5) ? 1.0 : 0.0;
    double mnew = mprev * 0.2 * (1.0 - sprev) + dot + bias;
    bool s = (mnew > 0.5);
    h1m[idx] = mnew;
    h1s[idx] = s ? 1 : 0;
    if (s) { s0 += v1n; s1 += v2n; s2 += 1.0; }
  }
  block_reduce3(s0, s1, s2, gacc);
}

// ---------------- fused: h2 update (blocks 0..255) + gen_x(t+1) (blocks 256+) ----
__global__ __launch_bounds__(256)
void fused_h2_genx(const unsigned char* __restrict__ h1s,
                   const float* __restrict__ W2T, const float* __restrict__ b2,
                   double* __restrict__ h2m, float* __restrict__ h2s,
                   float* __restrict__ h2sum, double* __restrict__ gacc,
                   float* __restrict__ out, const float* __restrict__ input,
                   v4i* __restrict__ XA, const float* __restrict__ v1,
                   const float* __restrict__ v2, int tnext, int last) {
  if (blockIdx.x < 256) {
    int lane = threadIdx.x & 63, wv = threadIdx.x >> 6;
    int b = blockIdx.x * 4 + wv;
    const unsigned char* hrow = h1s + (size_t)b * H1;
    double p[H2] = {};
    for (int i = lane; i < H1; i += 64) {
      if (hrow[i]) {
        #pragma unroll
        for (int j = 0; j < H2; j++) p[j] += (double)W2T[i * H2 + j];
      }
    }
    #pragma unroll
    for (int j = 0; j < H2; j++) {
      double v = p[j];
      #pragma unroll
      for (int off = 32; off > 0; off >>= 1) v += __shfl_xor(v, off, 64);
      p[j] = v;
    }
    if (lane < H2) {
      double red = 0;
      #pragma unroll
      for (int j = 0; j < H2; j++) red = (lane == j) ? p[j] : red;
      size_t idx = (size_t)b * H2 + lane;
      double m = h2m[idx] * 0.2 * (1.0 - (double)h2s[idx]) + red + (double)b2[lane];
      float s = (m > 0.5) ? 1.0f : 0.0f;
      float ns = h2sum[idx] + s;
      h2m[idx] = m; h2s[idx] = s; h2sum[idx] = ns;
      if (last) out[idx] = (float)((double)ns / (double)TT);
    }
    if (last && blockIdx.x == 0 && threadIdx.x < 3)
      out[(size_t)BB * H2 + threadIdx.x] = (float)gacc[threadIdx.x];
  } else {
    if (tnext >= TT) return;
    int gw = (blockIdx.x - 256) * 4 + (threadIdx.x >> 6);
    double s0, s1, s2;
    gen_wave(gw, tnext, input, XA, v1, v2, s0, s1, s2);
    block_reduce3(s0, s1, s2, gacc);
  }
}

// ---------------- launch ----------------
extern "C" void kernel_launch(void* const* d_in, const int* in_sizes, int n_in,
                              void* d_out, int out_size, void* d_ws, size_t ws_size,
                              hipStream_t stream) {
  const float* input = (const float*)d_in[0];
  const float* W1    = (const float*)d_in[1];
  const float* b1    = (const float*)d_in[2];
  const float* W2    = (const float*)d_in[3];
  const float* b2    = (const float*)d_in[4];
  const float* cmv   = (const float*)d_in[5];
  const int*   cmc   = (const int*)d_in[6];

  char* base = (char*)d_ws;
  // zeroed region
  double* h1m  = (double*)(base + 0);                  // 16,777,216 B
  double* h2m  = (double*)(base + 16777216);           //     81,920 B
  double* gacc = (double*)(base + 16859136);           //         64 B
  float*  h2s  = (float*)(base + 16859200);            //     40,960 B
  float*  h2sm = (float*)(base + 16900160);            //     40,960 B
  float*  v1   = (float*)(base + 16941120);            //     11,328 B
  float*  v2   = (float*)(base + 16952448);            //     11,328 B
  const size_t ZERO_BYTES = 16963776;
  // non-zeroed region
  float*  W2T  = (float*)(base + 16963776);            //     81,920 B
  unsigned char* h1s = (unsigned char*)(base + 17045696); // 2,097,152 B
  v4i*    XA   = (v4i*)(base + 19142848);              //    819,200 B
  v4i*    W1L  = (v4i*)(base + 19962048);              //  8,192,000 B  (end 28,154,048)

  hipMemsetAsync(d_ws, 0, ZERO_BYTES, stream);

  precompute_vals<<<(KK * UU) / 4, 256, 0, stream>>>(cmv, cmc, v1, v2);
  make_w2t<<<(H1 + 255) / 256, 256, 0, stream>>>(W2, W2T);
  make_limbs<<<(64 * NCH * 64) / 256, 256, 0, stream>>>(W1, W1L);
  gen0<<<100, 256, 0, stream>>>(input, XA, v1, v2, gacc);

  for (int t = 0; t < TT; t++) {
    step_h1<<<dim3(32, 16), 256, 0, stream>>>(XA, W1L, b1, h1m, h1s, v1, v2, gacc);
    fused_h2_genx<<<356, 256, 0, stream>>>(h1s, W2T, b2, h2m, h2s, h2sm, gacc,
                                           (float*)d_out, input, XA, v1, v2,
                                           t + 1, (t == TT - 1) ? 1 : 0);
  }
}

// Round 4
// 1035.702 us; speedup vs baseline: 3.7425x; 1.1335x over previous
//
#include <hip/hip_runtime.h>
#include <cstdint>
#include <cstddef>

// ---------------- problem constants (fixed by setup_inputs) ----------------
static constexpr int D_IN = 784;
static constexpr int H1   = 2048;
static constexpr int H2   = 10;
static constexpr int KK   = 10;
static constexpr int UU   = 2832;   // D_IN + H1
static constexpr int LL   = 128;
static constexpr int BB   = 1024;
static constexpr int TT   = 20;
static constexpr int HALF = BB * D_IN / 2;   // 401408 = 512*784
static constexpr int NCH  = 25;              // K chunks of 32 (784 -> 800 padded)

typedef int v4i  __attribute__((ext_vector_type(4)));
typedef int v16i __attribute__((ext_vector_type(16)));

// ---------------- JAX threefry2x32 (20 rounds), bit-exact ----------------
__device__ __forceinline__ uint32_t rotl32(uint32_t x, int d) {
  return (x << d) | (x >> (32 - d));
}
__device__ __forceinline__ void threefry2x32(uint32_t k0, uint32_t k1,
                                             uint32_t& x0, uint32_t& x1) {
  uint32_t ks2 = k0 ^ k1 ^ 0x1BD11BDAu;
  x0 += k0; x1 += k1;
#define TF_R(r) { x0 += x1; x1 = rotl32(x1, (r)); x1 ^= x0; }
  TF_R(13) TF_R(15) TF_R(26) TF_R(6)
  x0 += k1;  x1 += ks2 + 1u;
  TF_R(17) TF_R(29) TF_R(16) TF_R(24)
  x0 += ks2; x1 += k0 + 2u;
  TF_R(13) TF_R(15) TF_R(26) TF_R(6)
  x0 += k0;  x1 += k1 + 3u;
  TF_R(17) TF_R(29) TF_R(16) TF_R(24)
  x0 += k1;  x1 += ks2 + 4u;
  TF_R(13) TF_R(15) TF_R(26) TF_R(6)
  x0 += ks2; x1 += k0 + 5u;
#undef TF_R
}
__device__ __forceinline__ float bits_to_unif(uint32_t b) {
  uint32_t fb = (b >> 9) | 0x3F800000u;
  return __uint_as_float(fb) - 1.0f;
}

// ---------------- block-wide 3-way fp64 reduction + atomic ----------------
__device__ __forceinline__ double wave_red(double v) {
  #pragma unroll
  for (int off = 32; off > 0; off >>= 1) v += __shfl_down(v, off, 64);
  return v;
}
__device__ __forceinline__ void block_reduce3(double s0, double s1, double s2,
                                              double* gacc) {
  __shared__ double lds[3][4];
  int lane = threadIdx.x & 63, w = threadIdx.x >> 6;
  s0 = wave_red(s0); s1 = wave_red(s1); s2 = wave_red(s2);
  if (lane == 0) { lds[0][w] = s0; lds[1][w] = s1; lds[2][w] = s2; }
  __syncthreads();
  if (threadIdx.x == 0) {
    double t0 = 0, t1 = 0, t2 = 0;
    #pragma unroll
    for (int i = 0; i < 4; i++) { t0 += lds[0][i]; t1 += lds[1][i]; t2 += lds[2][i]; }
    atomicAdd(&gacc[0], t0); atomicAdd(&gacc[1], t1); atomicAdd(&gacc[2], t2);
  }
}

// ---------------- precompute val1/val2 (one wave per (k,u), ballot) ----------------
__global__ __launch_bounds__(256)
void precompute_vals(const float* __restrict__ vec, const int* __restrict__ cnt,
                     float* __restrict__ v1, float* __restrict__ v2) {
  int gw = (blockIdx.x * 256 + threadIdx.x) >> 6;
  int lane = threadIdx.x & 63;
  if (gw >= KK * UU) return;
  const float* p = vec + (size_t)gw * LL;
  float a = p[lane];
  float b = p[lane + 64];
  unsigned long long mlo = __ballot(a != 0.0f);
  unsigned long long mhi = __ballot(b != 0.0f);
  if (lane == 0) {
    int u = gw % UU;
    int c = cnt[gw];
    int last = mhi ? (127 - __builtin_clzll(mhi))
                   : (mlo ? (63 - __builtin_clzll(mlo)) : -1);
    if (c > 0) {
      if (last >= 0) atomicAdd(&v1[u], (float)(last - 1));
      atomicAdd(&v2[u], (float)c);
    }
  }
}

// ---------------- W2 transpose: W2T[i][j] = W2[j][i] ----------------
__global__ void make_w2t(const float* __restrict__ W2, float* __restrict__ W2T) {
  int i = blockIdx.x * 256 + threadIdx.x;
  if (i >= H1) return;
  #pragma unroll
  for (int j = 0; j < H2; j++) W2T[i * H2 + j] = W2[j * H1 + i];
}

// ---------------- W1 -> 5 signed base-256 int8 limbs, B-fragment order ----------
// W1L entry index: ((ntile*NCH + chunk)*5 + limb)*64 + lane  (16 B each)
// lane mapping: n = ntile*32 + (lane&31), k = chunk*32 + (lane>>5)*16 + j
__global__ __launch_bounds__(256)
void make_limbs(const float* __restrict__ W1, v4i* __restrict__ W1L) {
  int tid = blockIdx.x * 256 + threadIdx.x;   // 64*NCH*64 = 102400
  int lane = tid & 63;
  int tc = tid >> 6;                           // ntile*NCH + chunk
  int n = ((tc / NCH) << 5) + (lane & 31);
  int chunk = tc % NCH;
  int k0 = chunk * 32 + (lane >> 5) * 16;
  union { v4i v; signed char b[16]; } d[5];
  #pragma unroll
  for (int j = 0; j < 16; j++) {
    long long F = 0;
    int k = k0 + j;
    if (k < D_IN) {
      double w = (double)W1[(size_t)n * D_IN + k];
      F = llround(w * 0x1p40);
    }
    #pragma unroll
    for (int l = 0; l < 5; l++) {
      int dig = (int)((F + 128) & 255) - 128;
      d[l].b[j] = (signed char)dig;
      F = (F - dig) >> 8;
    }
  }
  #pragma unroll
  for (int l = 0; l < 5; l++) W1L[(size_t)(tc * 5 + l) * 64 + lane] = d[l].v;
}

// ---------------- spike generation, A-fragment order, + a1/a2/cs terms ----------
// XA entry index: (mtile*NCH + chunk)*64 + lane
// lane mapping: m = mtile*32 + (lane&31), k = chunk*32 + (lane>>5)*16 + j
__device__ __forceinline__ void gen_wave(int gw, int t,
    const float* __restrict__ input, v4i* __restrict__ XA,
    const float* __restrict__ v1, const float* __restrict__ v2,
    double& s0, double& s1, double& s2) {
  int lane = threadIdx.x & 63;
  int mtile = gw / NCH, chunk = gw - mtile * NCH;   // mtile in [0,16): m < 512
  int m = (mtile << 5) + (lane & 31);
  int k0 = chunk * 32 + (lane >> 5) * 16;
  uint32_t f0 = 0u, f1 = (uint32_t)t;
  threefry2x32(0u, 42u, f0, f1);
  union { v4i v; unsigned char b[16]; } r0, r1;
  s0 = 0; s1 = 0; s2 = 0;
  if (k0 < D_IN) {   // whole 16-group valid (784 = 24*32+16: only chunk24/half1 invalid)
    #pragma unroll
    for (int j = 0; j < 16; j++) {
      int k = k0 + j;
      uint32_t c0 = (uint32_t)(m * D_IN + k), c1 = c0 + (uint32_t)HALF;
      threefry2x32(f0, f1, c0, c1);
      float u0 = bits_to_unif(c0), u1 = bits_to_unif(c1);
      float i0 = input[(size_t)m * D_IN + k];
      float i1 = input[(size_t)(m + 512) * D_IN + k];
      unsigned char x0 = (i0 > u0) ? 1 : 0;
      unsigned char x1 = (i1 > u1) ? 1 : 0;
      r0.b[j] = x0; r1.b[j] = x1;
      double xsum = (double)(x0 + x1);
      s0 += xsum * (double)v1[k];
      s1 += xsum * (double)v2[k];
      s2 += xsum;
    }
  } else {
    r0.v = (v4i){0, 0, 0, 0};
    r1.v = (v4i){0, 0, 0, 0};
  }
  XA[(size_t)(mtile * NCH + chunk) * 64 + lane] = r0.v;
  XA[(size_t)((mtile + 16) * NCH + chunk) * 64 + lane] = r1.v;   // partner m+512
}

__global__ __launch_bounds__(256)
void gen0(const float* __restrict__ input, v4i* __restrict__ XA,
          const float* __restrict__ v1, const float* __restrict__ v2,
          double* __restrict__ gacc) {
  int gw = blockIdx.x * 4 + (threadIdx.x >> 6);    // 400 waves
  double s0, s1, s2;
  gen_wave(gw, 0, input, XA, v1, v2, s0, s1, s2);
  block_reduce3(s0, s1, s2, gacc);
}

// ---------------- h1 update: 5-limb i8 MFMA GEMM, wave tile 64m x 32n ----------
// Block = 4 waves -> 128m x 64n. Grid (32 n-blocks, 8 m-blocks): all m-blocks of
// one n-panel share an XCD (ids = bx mod 8) -> W1L panel is L2-resident (1 MB/XCD).
__global__ __launch_bounds__(256, 2)
void step_h1(const v4i* __restrict__ XA, const v4i* __restrict__ W1L,
             const float* __restrict__ b1, double* __restrict__ h1m,
             unsigned char* __restrict__ h1s, const float* __restrict__ v1,
             const float* __restrict__ v2, double* __restrict__ gacc) {
  int lane = threadIdx.x & 63, wv = threadIdx.x >> 6;
  int ntile = blockIdx.x * 2 + (wv & 1);           // [0,64)
  int mt0   = blockIdx.y * 4 + (wv >> 1) * 2;      // mtiles mt0, mt0+1 in [0,32)
  const v4i* a0p = XA + (size_t)mt0 * NCH * 64 + lane;
  const v4i* a1p = XA + (size_t)(mt0 + 1) * NCH * 64 + lane;
  const v4i* bp  = W1L + (size_t)ntile * NCH * 5 * 64 + lane;

  v16i c00 = {}, c10 = {}, c20 = {}, c30 = {}, c40 = {};   // limb x mhalf0
  v16i c01 = {}, c11 = {}, c21 = {}, c31 = {}, c41 = {};   // limb x mhalf1

  v4i A0 = a0p[0], A1 = a1p[0];
  v4i B0 = bp[0], B1 = bp[64], B2 = bp[128], B3 = bp[192], B4 = bp[256];

  #pragma unroll 1
  for (int c = 0; c < NCH; c++) {
    v4i nA0, nA1, nB0, nB1, nB2, nB3, nB4;
    if (c < NCH - 1) {
      nA0 = a0p[(c + 1) * 64];
      nA1 = a1p[(c + 1) * 64];
      const v4i* bq = bp + (size_t)(c + 1) * 5 * 64;
      nB0 = bq[0]; nB1 = bq[64]; nB2 = bq[128]; nB3 = bq[192]; nB4 = bq[256];
    }
    c00 = __builtin_amdgcn_mfma_i32_32x32x32_i8(A0, B0, c00, 0, 0, 0);
    c01 = __builtin_amdgcn_mfma_i32_32x32x32_i8(A1, B0, c01, 0, 0, 0);
    c10 = __builtin_amdgcn_mfma_i32_32x32x32_i8(A0, B1, c10, 0, 0, 0);
    c11 = __builtin_amdgcn_mfma_i32_32x32x32_i8(A1, B1, c11, 0, 0, 0);
    c20 = __builtin_amdgcn_mfma_i32_32x32x32_i8(A0, B2, c20, 0, 0, 0);
    c21 = __builtin_amdgcn_mfma_i32_32x32x32_i8(A1, B2, c21, 0, 0, 0);
    c30 = __builtin_amdgcn_mfma_i32_32x32x32_i8(A0, B3, c30, 0, 0, 0);
    c31 = __builtin_amdgcn_mfma_i32_32x32x32_i8(A1, B3, c31, 0, 0, 0);
    c40 = __builtin_amdgcn_mfma_i32_32x32x32_i8(A0, B4, c40, 0, 0, 0);
    c41 = __builtin_amdgcn_mfma_i32_32x32x32_i8(A1, B4, c41, 0, 0, 0);
    A0 = nA0; A1 = nA1;
    B0 = nB0; B1 = nB1; B2 = nB2; B3 = nB3; B4 = nB4;
  }

  // C/D layout (32x32): col=lane&31, row=(r&3)+8*(r>>2)+4*(lane>>5)
  int col = lane & 31;
  int rbase = (lane >> 5) * 4;
  int gn = (ntile << 5) + col;
  double bias = (double)b1[gn];
  double v1n = (double)v1[D_IN + gn], v2n = (double)v2[D_IN + gn];
  double s0 = 0, s1 = 0, s2 = 0;
  #pragma unroll
  for (int mh = 0; mh < 2; mh++) {
    const v16i& q0 = mh ? c01 : c00;
    const v16i& q1 = mh ? c11 : c10;
    const v16i& q2 = mh ? c21 : c20;
    const v16i& q3 = mh ? c31 : c30;
    const v16i& q4 = mh ? c41 : c40;
    int gmb = (mt0 + mh) << 5;
    #pragma unroll
    for (int r = 0; r < 16; r++) {
      int row = (r & 3) + 8 * (r >> 2) + rbase;
      int gm = gmb + row;
      double dot = ((((double)q4[r] * 256.0 + (double)q3[r]) * 256.0
                     + (double)q2[r]) * 256.0 + (double)q1[r]) * 256.0 + (double)q0[r];
      dot *= 0x1p-40;
      size_t idx = (size_t)gm * H1 + gn;
      double mprev = h1m[idx];
      double sprev = (mprev > 0.5) ? 1.0 : 0.0;
      double mnew = mprev * 0.2 * (1.0 - sprev) + dot + bias;
      bool s = (mnew > 0.5);
      h1m[idx] = mnew;
      h1s[idx] = s ? 1 : 0;
      if (s) { s0 += v1n; s1 += v2n; s2 += 1.0; }
    }
  }
  block_reduce3(s0, s1, s2, gacc);
}

// ---------------- fused: h2 update (blocks 0..255) + gen_x(t+1) (blocks 256+) ----
__global__ __launch_bounds__(256)
void fused_h2_genx(const unsigned char* __restrict__ h1s,
                   const float* __restrict__ W2T, const float* __restrict__ b2,
                   double* __restrict__ h2m, float* __restrict__ h2s,
                   float* __restrict__ h2sum, double* __restrict__ gacc,
                   float* __restrict__ out, const float* __restrict__ input,
                   v4i* __restrict__ XA, const float* __restrict__ v1,
                   const float* __restrict__ v2, int tnext, int last) {
  if (blockIdx.x < 256) {
    int lane = threadIdx.x & 63, wv = threadIdx.x >> 6;
    int b = blockIdx.x * 4 + wv;
    const unsigned char* hrow = h1s + (size_t)b * H1;
    double p[H2] = {};
    for (int i = lane; i < H1; i += 64) {
      if (hrow[i]) {
        #pragma unroll
        for (int j = 0; j < H2; j++) p[j] += (double)W2T[i * H2 + j];
      }
    }
    #pragma unroll
    for (int j = 0; j < H2; j++) {
      double v = p[j];
      #pragma unroll
      for (int off = 32; off > 0; off >>= 1) v += __shfl_xor(v, off, 64);
      p[j] = v;
    }
    if (lane < H2) {
      double red = 0;
      #pragma unroll
      for (int j = 0; j < H2; j++) red = (lane == j) ? p[j] : red;
      size_t idx = (size_t)b * H2 + lane;
      double m = h2m[idx] * 0.2 * (1.0 - (double)h2s[idx]) + red + (double)b2[lane];
      float s = (m > 0.5) ? 1.0f : 0.0f;
      float ns = h2sum[idx] + s;
      h2m[idx] = m; h2s[idx] = s; h2sum[idx] = ns;
      if (last) out[idx] = (float)((double)ns / (double)TT);
    }
    if (last && blockIdx.x == 0 && threadIdx.x < 3)
      out[(size_t)BB * H2 + threadIdx.x] = (float)gacc[threadIdx.x];
  } else {
    if (tnext >= TT) return;
    int gw = (blockIdx.x - 256) * 4 + (threadIdx.x >> 6);
    double s0, s1, s2;
    gen_wave(gw, tnext, input, XA, v1, v2, s0, s1, s2);
    block_reduce3(s0, s1, s2, gacc);
  }
}

// ---------------- launch ----------------
extern "C" void kernel_launch(void* const* d_in, const int* in_sizes, int n_in,
                              void* d_out, int out_size, void* d_ws, size_t ws_size,
                              hipStream_t stream) {
  const float* input = (const float*)d_in[0];
  const float* W1    = (const float*)d_in[1];
  const float* b1    = (const float*)d_in[2];
  const float* W2    = (const float*)d_in[3];
  const float* b2    = (const float*)d_in[4];
  const float* cmv   = (const float*)d_in[5];
  const int*   cmc   = (const int*)d_in[6];

  char* base = (char*)d_ws;
  // zeroed region
  double* h1m  = (double*)(base + 0);                  // 16,777,216 B
  double* h2m  = (double*)(base + 16777216);           //     81,920 B
  double* gacc = (double*)(base + 16859136);           //         64 B
  float*  h2s  = (float*)(base + 16859200);            //     40,960 B
  float*  h2sm = (float*)(base + 16900160);            //     40,960 B
  float*  v1   = (float*)(base + 16941120);            //     11,328 B
  float*  v2   = (float*)(base + 16952448);            //     11,328 B
  const size_t ZERO_BYTES = 16963776;
  // non-zeroed region
  float*  W2T  = (float*)(base + 16963776);            //     81,920 B
  unsigned char* h1s = (unsigned char*)(base + 17045696); // 2,097,152 B
  v4i*    XA   = (v4i*)(base + 19142848);              //    819,200 B
  v4i*    W1L  = (v4i*)(base + 19962048);              //  8,192,000 B  (end 28,154,048)

  hipMemsetAsync(d_ws, 0, ZERO_BYTES, stream);

  precompute_vals<<<(KK * UU) / 4, 256, 0, stream>>>(cmv, cmc, v1, v2);
  make_w2t<<<(H1 + 255) / 256, 256, 0, stream>>>(W2, W2T);
  make_limbs<<<(64 * NCH * 64) / 256, 256, 0, stream>>>(W1, W1L);
  gen0<<<100, 256, 0, stream>>>(input, XA, v1, v2, gacc);

  for (int t = 0; t < TT; t++) {
    step_h1<<<dim3(32, 8), 256, 0, stream>>>(XA, W1L, b1, h1m, h1s, v1, v2, gacc);
    fused_h2_genx<<<356, 256, 0, stream>>>(h1s, W2T, b2, h2m, h2s, h2sm, gacc,
                                           (float*)d_out, input, XA, v1, v2,
                                           t + 1, (t == TT - 1) ? 1 : 0);
  }
}